// Round 7
// baseline (201.544 us; speedup 1.0000x reference)
//
#include <hip/hip_runtime.h>
#include <hip/hip_bf16.h>

// Problem constants (from reference): z [65536,256] f32, embeddings [1024,256] f32
// out = quantized_st [65536*256] f32 ++ loss scalar (out_size = 16777217)
#define NROWS 65536
#define DIM   256
#define KCB   1024
#define ND    (NROWS * DIM)

typedef float f32x4  __attribute__((ext_vector_type(4)));
typedef short bf16x8 __attribute__((ext_vector_type(8)));  // 8 bf16 in 4 VGPRs
typedef short bf16x4 __attribute__((ext_vector_type(4)));  // 4 bf16 in 2 VGPRs

// workspace layout (bytes)
#define WS_LOSS   0        // float
#define WS_TICKET 64       // unsigned
#define WS_ENORM  256      // float[1024]
#define WS_E      8192     // bf16 permuted [16 chunks][2048 ids][8] = 512 KiB
#define WS_RMIN   532480   // unsigned[65536] packed row argmin = 256 KiB
// total needed: 532480 + 262144 = 794624 B

// fp32 -> bf16 bits, round-to-nearest-even
static __device__ __forceinline__ short f2bf(float f) {
    union { float f; unsigned u; } v; v.f = f;
    unsigned u = v.u;
    unsigned r = (u + 0x7fffu + ((u >> 16) & 1u)) >> 16;
    return (short)(unsigned short)r;
}

static __device__ __forceinline__ unsigned f2u(float f) {
    union { float f; unsigned u; } v; v.f = f; return v.u;
}
static __device__ __forceinline__ float u2f(unsigned u) {
    union { unsigned u; float f; } v; v.u = u; return v.f;
}

// ---------------------------------------------------------------------------
// Prep: e_norm (fp32) + E converted to bf16 in MFMA-staging-permuted order
// + row_min[65536] init (one entry per thread: grid 256x256 = 65536).
// Permuted id within a 64-row chunk: id = (t*8+s)*64 + q*16 + l
//   where embedding row = t*16+l, d-chunk c = s*4+q (8 bf16 per chunk).
// ---------------------------------------------------------------------------
__global__ __launch_bounds__(256) void prep_e(const float* __restrict__ E,
                                              float* __restrict__ enorm,
                                              bf16x4* __restrict__ wsE2,
                                              unsigned* __restrict__ row_min,
                                              float* __restrict__ loss_acc,
                                              unsigned* __restrict__ ticket) {
    const int tid = threadIdx.x;
    const int blk = blockIdx.x;            // 0..255, 4 embedding rows each

    if (blk == 0 && tid == 0) { *loss_acc = 0.f; *ticket = 0u; }
    row_min[blk * 256 + tid] = 0xFFFFFFFFu;   // argmin identity for packed keys

    const int w    = tid >> 6;             // 0..3: row within this block
    const int lane = tid & 63;             // float4 index within the row
    const int row  = blk * 4 + w;

    float4 f = ((const float4*)E)[row * 64 + lane];

    // row norm: each wave holds exactly one row -> full-wave butterfly
    float s = f.x * f.x + f.y * f.y + f.z * f.z + f.w * f.w;
#pragma unroll
    for (int m = 1; m < 64; m <<= 1) s += __shfl_xor(s, m, 64);
    if (lane == 0) enorm[row] = s;

    // permuted bf16 half-chunk write (8 B per lane; lane pairs are 16-B contiguous)
    bf16x4 o;
    o[0] = f2bf(f.x); o[1] = f2bf(f.y); o[2] = f2bf(f.z); o[3] = f2bf(f.w);
    const int kc = row >> 6;               // 64-row chunk
    const int rg = row & 63;
    const int t  = rg >> 4, l = rg & 15;
    const int c    = lane >> 1;            // 8-elem d-chunk 0..31
    const int half = lane & 1;
    const int sC   = c >> 2, q = c & 3;
    const int id   = (t * 8 + sC) * 64 + q * 16 + l;
    wsE2[(kc * 2048 + id) * 2 + half] = o;
}

// ---------------------------------------------------------------------------
// Main: fused score-GEMM (bf16 MFMA) + packed argmin, K-SPLIT across block
// pairs (ROUND-7).
//
// Diagnosis (R0-R6): all structures land 70-103 us with every pipe <35% —
// latency-bound at 2 waves/SIMD, because grid 512 = 2 blocks/CU caps
// occupancy (not VGPR at 120, not LDS at 34 KB). Halving rows/block would
// double total LDS-read traffic (each wave reads the whole B-chunk
// regardless of its row count) — so instead split the CODEBOOK: grid 1024,
// block b sweeps chunks [khalf*8, khalf*8+8) for rows (b&511)*128, where
// khalf = b>>9. Per-wave LDS reads halve, wave count doubles: total LDS,
// MFMA, VALU work exactly conserved, but now 4 blocks/CU (LDS 35.4 KB,
// launch_bounds(256,4) pins VGPR<=128) = 4 waves/SIMD = 2x latency hiding.
//
// Cross-block argmin merge is one u32 atomicMin per row: the packed key
// (verified R5/R6: biased-positive score bits | kidx) is a global total
// order, min is commutative/order-independent, ties -> lowest kidx =
// reference argmin semantics. Gather + loss finalize move to vq_gather
// (kernel boundary = cross-XCD coherence fence for the atomics).
// Sum ||z||^2 is argmin-independent -> added here by khalf==0 blocks.
// ---------------------------------------------------------------------------
__global__ __launch_bounds__(256, 4) void vq_main(const float* __restrict__ Z,
                                                  const float* __restrict__ enorm,
                                                  const bf16x8* __restrict__ wsE,
                                                  unsigned* __restrict__ row_min,
                                                  float* __restrict__ loss_acc) {
    __shared__ bf16x8 Es[2048];         // 32 KiB E chunk, staging order
    __shared__ float  enorm_s[512];     // 2 KiB: this half's norms, pre-biased +1
    __shared__ float  znorm_s[128];
    __shared__ float  blk_loss;

    const int tid  = threadIdx.x;
    const int w    = tid >> 6;
    const int lane = tid & 63;
    const int q    = lane >> 4;
    const int l    = lane & 15;
    const int blk  = blockIdx.x;        // 0..1023
    const int rb   = (blk & 511) * 128; // row base (shared by the pair)
    const int kc0  = (blk >> 9) * 8;    // chunk base: 0 or 8

    if (tid == 0) blk_loss = 0.f;

    // this half's e-norm table (512 floats), biased +1.0 for the u32-order trick
    if (tid < 128) {
        float4 e4 = ((const float4*)enorm)[kc0 * 16 + tid];
        e4.x += 1.f; e4.y += 1.f; e4.z += 1.f; e4.w += 1.f;
        ((float4*)enorm_s)[tid] = e4;
    }

    // ---- load A fragments (z rows) into registers; accumulate ||z||^2 fp32 ----
    bf16x8 zf[2][8];
    const float4* Z4 = (const float4*)Z;
#pragma unroll
    for (int rt = 0; rt < 2; ++rt) {
        int row = rb + w * 32 + rt * 16 + l;
        float zn = 0.f;
#pragma unroll
        for (int s = 0; s < 8; ++s) {
            int fi = row * 64 + s * 8 + q * 2;
            float4 f0 = Z4[fi], f1 = Z4[fi + 1];
            zn += f0.x * f0.x + f0.y * f0.y + f0.z * f0.z + f0.w * f0.w;
            zn += f1.x * f1.x + f1.y * f1.y + f1.z * f1.z + f1.w * f1.w;
            bf16x8 o;
            o[0] = f2bf(f0.x); o[1] = f2bf(f0.y); o[2] = f2bf(f0.z); o[3] = f2bf(f0.w);
            o[4] = f2bf(f1.x); o[5] = f2bf(f1.y); o[6] = f2bf(f1.z); o[7] = f2bf(f1.w);
            zf[rt][s] = o;
        }
        // each lane holds 64 of the row's 256 values; sum across the 4 q-lanes
        zn += __shfl_xor(zn, 16, 64);
        zn += __shfl_xor(zn, 32, 64);
        if (q == 0) znorm_s[w * 32 + rt * 16 + l] = zn;
    }

    // packed running argmin: high 22 bits = biased-score bits, low 10 = kidx
    unsigned minp[2][4];
#pragma unroll
    for (int rt = 0; rt < 2; ++rt)
#pragma unroll
        for (int r = 0; r < 4; ++r) minp[rt][r] = 0xFFFFFFFFu;

    // ---- K sweep over this block's 8 chunks (verified R0 2-barrier loop) ----
    for (int kcL = 0; kcL < 8; ++kcL) {
        __syncthreads();   // previous chunk's reads done (also covers init)
#pragma unroll
        for (int j = 0; j < 8; ++j) {
            int id = tid + 256 * j;
            Es[id] = wsE[(kc0 + kcL) * 2048 + id];
        }
        __syncthreads();   // Es ready for all waves

        f32x4 acc[2][4];
#pragma unroll
        for (int rt = 0; rt < 2; ++rt)
#pragma unroll
            for (int t = 0; t < 4; ++t) acc[rt][t] = (f32x4){0.f, 0.f, 0.f, 0.f};

#pragma unroll
        for (int s = 0; s < 8; ++s) {
            bf16x8 b0 = Es[(0 * 8 + s) * 64 + lane];
            bf16x8 b1 = Es[(1 * 8 + s) * 64 + lane];
            bf16x8 b2 = Es[(2 * 8 + s) * 64 + lane];
            bf16x8 b3 = Es[(3 * 8 + s) * 64 + lane];
            acc[0][0] = __builtin_amdgcn_mfma_f32_16x16x32_bf16(zf[0][s], b0, acc[0][0], 0, 0, 0);
            acc[0][1] = __builtin_amdgcn_mfma_f32_16x16x32_bf16(zf[0][s], b1, acc[0][1], 0, 0, 0);
            acc[0][2] = __builtin_amdgcn_mfma_f32_16x16x32_bf16(zf[0][s], b2, acc[0][2], 0, 0, 0);
            acc[0][3] = __builtin_amdgcn_mfma_f32_16x16x32_bf16(zf[0][s], b3, acc[0][3], 0, 0, 0);
            acc[1][0] = __builtin_amdgcn_mfma_f32_16x16x32_bf16(zf[1][s], b0, acc[1][0], 0, 0, 0);
            acc[1][1] = __builtin_amdgcn_mfma_f32_16x16x32_bf16(zf[1][s], b1, acc[1][1], 0, 0, 0);
            acc[1][2] = __builtin_amdgcn_mfma_f32_16x16x32_bf16(zf[1][s], b2, acc[1][2], 0, 0, 0);
            acc[1][3] = __builtin_amdgcn_mfma_f32_16x16x32_bf16(zf[1][s], b3, acc[1][3], 0, 0, 0);
        }

        // min update: C/D layout col = lane&15 (embedding), row = q*4+reg (z row)
        // sc' = (en+1) - 2*dot in (0.4,1.6): positive -> u32 order == f32 order
#pragma unroll
        for (int t = 0; t < 4; ++t) {
            float    en   = enorm_s[kcL * 64 + t * 16 + l];            // pre-biased +1
            unsigned kidx = (unsigned)((kc0 + kcL) * 64 + t * 16 + l); // < 1024
#pragma unroll
            for (int rt = 0; rt < 2; ++rt)
#pragma unroll
                for (int r = 0; r < 4; ++r) {
                    float sc = __builtin_fmaf(-2.f, acc[rt][t][r], en);
                    unsigned key = (f2u(sc) & 0xFFFFFC00u) | kidx;
                    minp[rt][r] = key < minp[rt][r] ? key : minp[rt][r];
                }
        }
    }

    // ---- cross-lane argmin + cross-block merge via device-scope atomicMin ----
#pragma unroll
    for (int rt = 0; rt < 2; ++rt)
#pragma unroll
        for (int r = 0; r < 4; ++r) {
            unsigned p = minp[rt][r];
#pragma unroll
            for (int m = 1; m <= 8; m <<= 1) {
                unsigned op = (unsigned)__shfl_xor((int)p, m, 64);
                p = op < p ? op : p;
            }
            if (l == 0) {
                int rloc = w * 32 + rt * 16 + q * 4 + r;
                atomicMin(&row_min[rb + rloc], p);
            }
        }

    // ---- sum ||z||^2 contribution (argmin-independent): khalf==0 blocks only ----
    if (kc0 == 0) {
        if (tid < 128) atomicAdd(&blk_loss, znorm_s[tid]);
        __syncthreads();
        if (tid == 0) atomicAdd(loss_acc, blk_loss);
    }
}

// ---------------------------------------------------------------------------
// Gather + loss finalize. Runs after vq_main (same stream => all atomicMin
// results visible). 512 blocks x 128 rows.
// ---------------------------------------------------------------------------
__global__ __launch_bounds__(256) void vq_gather(const float* __restrict__ E,
                                                 const unsigned* __restrict__ row_min,
                                                 float* __restrict__ out,
                                                 float* __restrict__ loss_acc,
                                                 unsigned* __restrict__ ticket) {
    __shared__ int   closest_s[128];
    __shared__ float vbuf[128];

    const int tid = threadIdx.x;
    const int blk = blockIdx.x;           // 0..511

    if (tid < 128) {
        unsigned key = row_min[blk * 128 + tid];
        closest_s[tid] = (int)(key & 1023u);
        vbuf[tid] = u2f(key & 0xFFFFFC00u) - 1.0f;   // min ||z-e||^2 - ||z||^2 part
    }
    __syncthreads();

    // gather: out rows = E[closest] in fp32 (exact values)
    const float4* E4 = (const float4*)E;
    float4* O4 = (float4*)out;
#pragma unroll
    for (int u = 0; u < 32; ++u) {
        int idx = u * 256 + tid;          // 0..8191
        int row = idx >> 6;
        int c4  = idx & 63;
        O4[(blk * 128 + row) * 64 + c4] = E4[closest_s[row] * 64 + c4];
    }

    // block loss partial (sum of min biased-scores) + last-block finalize
    if (tid < 64) {
        float v = vbuf[tid] + vbuf[tid + 64];
#pragma unroll
        for (int m = 1; m < 64; m <<= 1) v += __shfl_xor(v, m, 64);
        if (tid == 0) {
            atomicAdd(loss_acc, v);
            __threadfence();              // loss add visible before ticket bump
            unsigned tk = atomicAdd(ticket, 1u);
            if (tk == 511u) {
                float total = atomicAdd(loss_acc, 0.0f);   // coherent read
                out[ND] = 1.25f * total / (float)ND;       // codebook + 0.25*commitment
            }
        }
    }
}

extern "C" void kernel_launch(void* const* d_in, const int* in_sizes, int n_in,
                              void* d_out, int out_size, void* d_ws, size_t ws_size,
                              hipStream_t stream) {
    const float* z = (const float*)d_in[0];
    const float* e = (const float*)d_in[1];
    float* out = (float*)d_out;
    char*  ws  = (char*)d_ws;
    float*    loss_acc = (float*)(ws + WS_LOSS);
    unsigned* ticket   = (unsigned*)(ws + WS_TICKET);
    float*    enorm    = (float*)(ws + WS_ENORM);
    bf16x8*   wsE      = (bf16x8*)(ws + WS_E);
    bf16x4*   wsE2     = (bf16x4*)(ws + WS_E);
    unsigned* row_min  = (unsigned*)(ws + WS_RMIN);

    prep_e<<<256, 256, 0, stream>>>(e, enorm, wsE2, row_min, loss_acc, ticket);
    vq_main<<<1024, 256, 0, stream>>>(z, enorm, wsE, row_min, loss_acc);
    vq_gather<<<512, 256, 0, stream>>>(e, row_min, out, loss_acc, ticket);
}

// Round 8
// 156.185 us; speedup vs baseline: 1.2904x; 1.2904x over previous
//
#include <hip/hip_runtime.h>
#include <hip/hip_bf16.h>

// Problem constants (from reference): z [65536,256] f32, embeddings [1024,256] f32
// out = quantized_st [65536*256] f32 ++ loss scalar (out_size = 16777217)
#define NROWS 65536
#define DIM   256
#define KCB   1024
#define ND    (NROWS * DIM)

typedef float f32x4  __attribute__((ext_vector_type(4)));
typedef short bf16x8 __attribute__((ext_vector_type(8)));  // 8 bf16 in 4 VGPRs
typedef short bf16x4 __attribute__((ext_vector_type(4)));  // 4 bf16 in 2 VGPRs

// workspace layout (bytes)
#define WS_LOSS   0      // float
#define WS_TICKET 64     // unsigned
#define WS_ENORM  256    // float[1024]
#define WS_E      8192   // bf16 permuted [16 chunks][2048 ids][8] = 512 KiB
// total needed: 8192 + 524288 = 532480 B

// fp32 -> bf16 bits, round-to-nearest-even
static __device__ __forceinline__ short f2bf(float f) {
    union { float f; unsigned u; } v; v.f = f;
    unsigned u = v.u;
    unsigned r = (u + 0x7fffu + ((u >> 16) & 1u)) >> 16;
    return (short)(unsigned short)r;
}

static __device__ __forceinline__ unsigned f2u(float f) {
    union { float f; unsigned u; } v; v.f = f; return v.u;
}
static __device__ __forceinline__ float u2f(unsigned u) {
    union { unsigned u; float f; } v; v.u = u; return v.f;
}

// async global->LDS, 16 B per lane. LDS dest is wave-uniform base + lane*16
// at every call site (id = tid + 256*j => within a wave: base + lane*16B).
static __device__ __forceinline__ void gll16(const void* g, void* l) {
    __builtin_amdgcn_global_load_lds(
        (const __attribute__((address_space(1))) unsigned*)g,
        (__attribute__((address_space(3))) unsigned*)l, 16, 0, 0);
}

// ---------------------------------------------------------------------------
// Prep: e_norm (fp32) + E converted to bf16 in MFMA-staging-permuted order.
// Permuted id within a 64-row chunk: id = (t*8+s)*64 + q*16 + l
//   where embedding row = t*16+l, d-chunk c = s*4+q (8 bf16 per chunk).
// 256 blocks; each block owns 4 rows; each thread reads ONE coalesced
// float4 (16 B/lane), wave-reduces the row norm, writes its 8-B half-chunk.
// ---------------------------------------------------------------------------
__global__ __launch_bounds__(256) void prep_e(const float* __restrict__ E,
                                              float* __restrict__ enorm,
                                              bf16x4* __restrict__ wsE2,
                                              float* __restrict__ loss_acc,
                                              unsigned* __restrict__ ticket) {
    const int tid = threadIdx.x;
    const int blk = blockIdx.x;            // 0..255, 4 embedding rows each

    if (blk == 0 && tid == 0) { *loss_acc = 0.f; *ticket = 0u; }

    const int w    = tid >> 6;             // 0..3: row within this block
    const int lane = tid & 63;             // float4 index within the row
    const int row  = blk * 4 + w;

    float4 f = ((const float4*)E)[row * 64 + lane];

    // row norm: each wave holds exactly one row -> full-wave butterfly
    float s = f.x * f.x + f.y * f.y + f.z * f.z + f.w * f.w;
#pragma unroll
    for (int m = 1; m < 64; m <<= 1) s += __shfl_xor(s, m, 64);
    if (lane == 0) enorm[row] = s;

    // permuted bf16 half-chunk write (8 B per lane; lane pairs are 16-B contiguous)
    bf16x4 o;
    o[0] = f2bf(f.x); o[1] = f2bf(f.y); o[2] = f2bf(f.z); o[3] = f2bf(f.w);
    const int kc = row >> 6;               // 64-row chunk
    const int rg = row & 63;
    const int t  = rg >> 4, l = rg & 15;
    const int c    = lane >> 1;            // 8-elem d-chunk 0..31
    const int half = lane & 1;
    const int sC   = c >> 2, q = c & 3;
    const int id   = (t * 8 + sC) * 64 + q * 16 + l;
    wsE2[(kc * 2048 + id) * 2 + half] = o;
}

// ---------------------------------------------------------------------------
// Main: fused score-GEMM (bf16 MFMA) + packed argmin + gather + loss.
// Block = 256 thr (4 waves), 128 z-rows, grid 512 (2 blocks/CU).
//
// ROUND-8: the untested matrix cell {global_load_lds dbuf, VGPR<=128}.
//  * R1 (gll, runtime-indexed buf) and R2 (gll, static bufs) both regressed,
//    but R2 sat at VGPR 136 -> reg-quantum rounds to 256 -> 1 block/CU,
//    which alone explains its 102 us. gll staging itself was never tested
//    at 2 blocks/CU.
//  * Packed argmin keys (verified R5-R7) freed ~32 regs; dropping the
//    stg[8] register buffer frees 32 more -> ~90-120 total, under the
//    measured 128 quantum.
//  * gll removes 8 ds_write_b128/thread/chunk (~1 MB/CU off the LDS pipe,
//    which saturates in compute bursts — R7's occupancy experiment), the
//    VGPR round-trip, and the commit serialization. Loads are issued at
//    the TOP of each compute phase: ~700 cycles of ds_read+MFMA cover the
//    L2 latency, so the end-of-phase barrier's vmcnt(0) drain is free.
//  * Static Es0/Es1 + one barrier per chunk.
// ---------------------------------------------------------------------------
__global__ __launch_bounds__(256, 2) void vq_main(const float* __restrict__ Z,
                                                  const float* __restrict__ E,
                                                  const float* __restrict__ enorm,
                                                  const bf16x8* __restrict__ wsE,
                                                  float* __restrict__ out,
                                                  float* __restrict__ loss_acc,
                                                  unsigned* __restrict__ ticket) {
    __shared__ bf16x8 Es0[2048];        // 32 KiB buffer A (even chunks)
    __shared__ bf16x8 Es1[2048];        // 32 KiB buffer B (odd chunks)
    __shared__ float  enorm_s[KCB];     // 4 KiB: all 1024 norms, pre-biased +1.0
    __shared__ float  znorm_s[128];
    __shared__ int    closest_s[128];
    __shared__ float  blk_loss;

    const int tid  = threadIdx.x;
    const int w    = tid >> 6;
    const int lane = tid & 63;
    const int q    = lane >> 4;
    const int l    = lane & 15;
    const int blk  = blockIdx.x;

    if (tid == 0) blk_loss = 0.f;

    // issue chunk-0 DMA NOW: flies under enorm/zf loading below
#pragma unroll
    for (int j = 0; j < 8; ++j)
        gll16(&wsE[tid + 256 * j], &Es0[tid + 256 * j]);

    // whole e-norm table once, biased by +1.0 for the u32-order trick
    {
        float4 e4 = ((const float4*)enorm)[tid];
        e4.x += 1.f; e4.y += 1.f; e4.z += 1.f; e4.w += 1.f;
        ((float4*)enorm_s)[tid] = e4;
    }

    // ---- load A fragments (z rows) into registers; accumulate ||z||^2 fp32 ----
    bf16x8 zf[2][8];
    const float4* Z4 = (const float4*)Z;
#pragma unroll
    for (int rt = 0; rt < 2; ++rt) {
        int row = blk * 128 + w * 32 + rt * 16 + l;
        float zn = 0.f;
#pragma unroll
        for (int s = 0; s < 8; ++s) {
            int fi = row * 64 + s * 8 + q * 2;
            float4 f0 = Z4[fi], f1 = Z4[fi + 1];
            zn += f0.x * f0.x + f0.y * f0.y + f0.z * f0.z + f0.w * f0.w;
            zn += f1.x * f1.x + f1.y * f1.y + f1.z * f1.z + f1.w * f1.w;
            bf16x8 o;
            o[0] = f2bf(f0.x); o[1] = f2bf(f0.y); o[2] = f2bf(f0.z); o[3] = f2bf(f0.w);
            o[4] = f2bf(f1.x); o[5] = f2bf(f1.y); o[6] = f2bf(f1.z); o[7] = f2bf(f1.w);
            zf[rt][s] = o;
        }
        // each lane holds 64 of the row's 256 values; sum across the 4 q-lanes
        zn += __shfl_xor(zn, 16, 64);
        zn += __shfl_xor(zn, 32, 64);
        if (q == 0) znorm_s[w * 32 + rt * 16 + l] = zn;
    }

    // packed running argmin: high 22 bits = biased-score bits, low 10 = kidx
    unsigned minp[2][4];
#pragma unroll
    for (int rt = 0; rt < 2; ++rt)
#pragma unroll
        for (int r = 0; r < 4; ++r) minp[rt][r] = 0xFFFFFFFFu;

    __syncthreads();   // drains vmcnt: chunk 0 in Es0; enorm/znorm/blk_loss visible

    // issue next chunk's DMA into the other static buffer (top of phase)
#define GLL(EDST, KC)                                                        \
    _Pragma("unroll")                                                        \
    for (int j = 0; j < 8; ++j)                                              \
        gll16(&wsE[(KC) * 2048 + tid + 256 * j], &(EDST)[tid + 256 * j]);

    // compute one 64-embedding chunk from ESRC; update running packed argmin
#define COMPUTE(ESRC, KC)                                                    \
    {                                                                        \
        f32x4 acc[2][4];                                                     \
        _Pragma("unroll")                                                    \
        for (int rt = 0; rt < 2; ++rt)                                       \
            _Pragma("unroll")                                                \
            for (int t = 0; t < 4; ++t) acc[rt][t] = (f32x4){0.f,0.f,0.f,0.f};\
        _Pragma("unroll")                                                    \
        for (int s = 0; s < 8; ++s) {                                        \
            bf16x8 b0 = (ESRC)[(0 * 8 + s) * 64 + lane];                     \
            bf16x8 b1 = (ESRC)[(1 * 8 + s) * 64 + lane];                     \
            bf16x8 b2 = (ESRC)[(2 * 8 + s) * 64 + lane];                     \
            bf16x8 b3 = (ESRC)[(3 * 8 + s) * 64 + lane];                     \
            acc[0][0] = __builtin_amdgcn_mfma_f32_16x16x32_bf16(zf[0][s], b0, acc[0][0], 0, 0, 0); \
            acc[0][1] = __builtin_amdgcn_mfma_f32_16x16x32_bf16(zf[0][s], b1, acc[0][1], 0, 0, 0); \
            acc[0][2] = __builtin_amdgcn_mfma_f32_16x16x32_bf16(zf[0][s], b2, acc[0][2], 0, 0, 0); \
            acc[0][3] = __builtin_amdgcn_mfma_f32_16x16x32_bf16(zf[0][s], b3, acc[0][3], 0, 0, 0); \
            acc[1][0] = __builtin_amdgcn_mfma_f32_16x16x32_bf16(zf[1][s], b0, acc[1][0], 0, 0, 0); \
            acc[1][1] = __builtin_amdgcn_mfma_f32_16x16x32_bf16(zf[1][s], b1, acc[1][1], 0, 0, 0); \
            acc[1][2] = __builtin_amdgcn_mfma_f32_16x16x32_bf16(zf[1][s], b2, acc[1][2], 0, 0, 0); \
            acc[1][3] = __builtin_amdgcn_mfma_f32_16x16x32_bf16(zf[1][s], b3, acc[1][3], 0, 0, 0); \
        }                                                                    \
        /* C/D layout: col = lane&15 (embedding), row = q*4+reg (z row) */   \
        /* sc' = (en+1) - 2*dot in (0.4,1.6): u32 order == f32 order */      \
        _Pragma("unroll")                                                    \
        for (int t = 0; t < 4; ++t) {                                        \
            float    en   = enorm_s[(KC) * 64 + t * 16 + l];                 \
            unsigned kidx = (unsigned)((KC) * 64 + t * 16 + l);              \
            _Pragma("unroll")                                                \
            for (int rt = 0; rt < 2; ++rt)                                   \
                _Pragma("unroll")                                            \
                for (int r = 0; r < 4; ++r) {                                \
                    float sc = __builtin_fmaf(-2.f, acc[rt][t][r], en);      \
                    unsigned key = (f2u(sc) & 0xFFFFFC00u) | kidx;           \
                    minp[rt][r] = key < minp[rt][r] ? key : minp[rt][r];     \
                }                                                            \
        }                                                                    \
    }

    // ---- K sweep: gll double-buffer, ONE barrier per chunk ----
    for (int kk = 0; kk < 8; ++kk) {
        const int k0 = kk * 2;
        GLL(Es1, k0 + 1)                 // DMA odd chunk; flies under MFMAs
        COMPUTE(Es0, k0)
        __syncthreads();                 // Es1 complete (vmcnt drain); Es0 free
        if (kk < 7) { GLL(Es0, k0 + 2) } // DMA next even chunk
        COMPUTE(Es1, k0 + 1)
        __syncthreads();                 // Es0 complete; Es1 free
    }
#undef GLL
#undef COMPUTE

    // ---- cross-lane argmin: u32 min over the 16 column-lanes of each quad ----
    float lossp = 0.f;
#pragma unroll
    for (int rt = 0; rt < 2; ++rt)
#pragma unroll
        for (int r = 0; r < 4; ++r) {
            unsigned p = minp[rt][r];
#pragma unroll
            for (int m = 1; m <= 8; m <<= 1) {
                unsigned op = (unsigned)__shfl_xor((int)p, m, 64);
                p = op < p ? op : p;
            }
            if (l == 0) {
                int rloc = w * 32 + rt * 16 + q * 4 + r;
                closest_s[rloc] = (int)(p & 1023u);
                float v = u2f(p & 0xFFFFFC00u) - 1.0f;
                lossp += v + znorm_s[rloc];   // ||z||^2 + ||e*||^2 - 2 z.e*
            }
        }
    if (l == 0) atomicAdd(&blk_loss, lossp);
    __syncthreads();                      // closest_s + blk_loss visible

    // ---- gather epilogue: out rows = E[closest] in fp32 (exact values) ----
    const float4* E4 = (const float4*)E;
    float4* O4 = (float4*)out;
#pragma unroll
    for (int u = 0; u < 32; ++u) {
        int idx = u * 256 + tid;          // 0..8191
        int row = idx >> 6;
        int c4  = idx & 63;
        int k   = closest_s[row];
        O4[(blk * 128 + row) * 64 + c4] = E4[k * 64 + c4];
    }

    // ---- loss finalize: last block through the ticket writes the scalar ----
    if (tid == 0) {
        atomicAdd(loss_acc, blk_loss);
        __threadfence();                  // loss add visible before ticket bump
        unsigned tk = atomicAdd(ticket, 1u);
        if (tk == (unsigned)(gridDim.x - 1)) {
            float total = atomicAdd(loss_acc, 0.0f);   // coherent read of final sum
            out[ND] = 1.25f * total / (float)ND;       // codebook + 0.25*commitment
        }
    }
}

extern "C" void kernel_launch(void* const* d_in, const int* in_sizes, int n_in,
                              void* d_out, int out_size, void* d_ws, size_t ws_size,
                              hipStream_t stream) {
    const float* z = (const float*)d_in[0];
    const float* e = (const float*)d_in[1];
    float* out = (float*)d_out;
    char*  ws  = (char*)d_ws;
    float*    loss_acc = (float*)(ws + WS_LOSS);
    unsigned* ticket   = (unsigned*)(ws + WS_TICKET);
    float*    enorm    = (float*)(ws + WS_ENORM);
    bf16x8*   wsE      = (bf16x8*)(ws + WS_E);
    bf16x4*   wsE2     = (bf16x4*)(ws + WS_E);

    prep_e<<<256, 256, 0, stream>>>(e, enorm, wsE2, loss_acc, ticket);
    vq_main<<<512, 256, 0, stream>>>(z, e, enorm, wsE, out, loss_acc, ticket);
}